// Round 22
// baseline (702.604 us; speedup 1.0000x reference)
//
#include <hip/hip_runtime.h>
#include <hip/hip_bf16.h>
#include <math.h>

#define B_ 4
#define S_ 100
#define T_ 2048
#define DM 128
#define NH 8
#define DH 16
#define NL 6
#define DFFN 512
#define NSPL 4

#define SQRT_D 11.313708498984761f   // sqrt(128)
#define LN10K  9.210340371976184f    // ln(10000)
#define QSCALE 0.36067376022224085f  // 0.25 * log2(e)  (softmax in exp2 domain)

typedef _Float16 v4h __attribute__((ext_vector_type(4)));
typedef _Float16 v8h __attribute__((ext_vector_type(8)));
typedef float    v4f __attribute__((ext_vector_type(4)));

__device__ __forceinline__ float fexp2(float x) { return __builtin_amdgcn_exp2f(x); }

__device__ __forceinline__ v4f mfma16(v4h a, v4h b, v4f c) {
    return __builtin_amdgcn_mfma_f32_16x16x16f16(a, b, c, 0, 0, 0);
}

__device__ __forceinline__ void gload_lds16(const void* g, void* l) {
    __builtin_amdgcn_global_load_lds(
        (const __attribute__((address_space(1))) unsigned int*)g,
        (__attribute__((address_space(3))) unsigned int*)l, 16, 0, 0);
}

// ---------------------------------------------------------------- posenc
__device__ __forceinline__ float pe_val(int pos, int d) {
    int i = d >> 1;
    float dv = __expf((float)i * (-2.0f * LN10K / 128.0f));
    float ang = (float)pos * dv;
    return (d & 1) ? __cosf(ang) : __sinf(ang);
}

// ---------------------------------------------------------------- weight f32->f16 conversion (once per call)
__global__ __launch_bounds__(256) void conv_w(
    const float* __restrict__ p0, const float* __restrict__ p1,
    const float* __restrict__ p2, const float* __restrict__ p3,
    const float* __restrict__ p4, const float* __restrict__ p5,
    const float* __restrict__ p6, const float* __restrict__ p7,
    const float* __restrict__ p8, const float* __restrict__ p9,
    _Float16* __restrict__ out)
{
    int seg = blockIdx.y;
    const float* s; int sz; long off;
    switch (seg) {
        case 0: s = p0; sz = 294912; off = 0;       break;
        case 1: s = p1; sz = 98304;  off = 294912;  break;
        case 2: s = p2; sz = 393216; off = 393216;  break;
        case 3: s = p3; sz = 393216; off = 786432;  break;
        case 4: s = p4; sz = 294912; off = 1179648; break;
        case 5: s = p5; sz = 98304;  off = 1474560; break;
        case 6: s = p6; sz = 294912; off = 1572864; break;
        case 7: s = p7; sz = 98304;  off = 1867776; break;
        case 8: s = p8; sz = 393216; off = 1966080; break;
        default: s = p9; sz = 393216; off = 2359296; break;
    }
    int idx = (blockIdx.x * 256 + threadIdx.x) * 4;
    if (idx >= sz) return;
    float4 v = *(const float4*)(s + idx);
    v4h h = { (_Float16)v.x, (_Float16)v.y, (_Float16)v.z, (_Float16)v.w };
    *(v4h*)(out + off + idx) = h;
}

// ---------------------------------------------------------------- embeds (f16)
__global__ __launch_bounds__(256) void embed_src_kernel(
    const int* __restrict__ src, const float* __restrict__ emb,
    _Float16* __restrict__ outh)
{
    int idx = blockIdx.x * 256 + threadIdx.x;
    if (idx >= B_ * S_ * DM) return;
    int d = idx & 127;
    int row = idx >> 7;
    int b = row / S_;
    int tok = src[row];
    float v = emb[tok * DM + d] * SQRT_D + pe_val(b, d);
    outh[idx] = (_Float16)v;
}

__global__ __launch_bounds__(256) void embed_tgt_kernel(
    const float* __restrict__ tgt, const float* __restrict__ fw,
    const float* __restrict__ fb, _Float16* __restrict__ outh)
{
    int idx = blockIdx.x * 256 + threadIdx.x;
    if (idx >= B_ * T_ * DM) return;
    int d = idx & 127;
    int row = idx >> 7;
    int b = row >> 11;
    float v = (tgt[row] * fw[d] + fb[d]) * SQRT_D + pe_val(b, d);
    outh[idx] = (_Float16)v;
}

// ---------------------------------------------------------------- f16 MFMA GEMM (NT), BM=128 BN=64 BK=64, 256 thr
// MODE 2: attention pack (q scaled, k, v-transposed); z-strided for multi-layer batch.
template<int MODE>
__global__ __launch_bounds__(256) void gemm_h(
    const _Float16* __restrict__ A, const _Float16* __restrict__ W,
    const float* __restrict__ bias,
    _Float16* __restrict__ Ch,
    _Float16* __restrict__ qo, _Float16* __restrict__ ko, _Float16* __restrict__ vo,
    int M, int N, int K, int L, int Lkp, int part_off, int Lshift,
    long zws, int zbs, long zks, long zvs)
{
    if (MODE == 2) {
        int zi = blockIdx.z;
        W += (size_t)zi * zws;
        bias += (size_t)zi * zbs;
        ko += (size_t)zi * zks;
        vo += (size_t)zi * zvs;
    }
    __shared__ _Float16 As[128][72];
    __shared__ _Float16 Ws[64][72];
    const int t = threadIdx.x;
    const int wave = t >> 6, lane = t & 63;
    const int col16 = lane & 15, grp = lane >> 4;
    const int row0 = blockIdx.x * 128, col0 = blockIdx.y * 64;
    const int wrow0 = (wave >> 1) * 64, wcol0 = (wave & 1) * 32;

    v4f acc[4][2];
    #pragma unroll
    for (int m = 0; m < 4; m++)
        #pragma unroll
        for (int n = 0; n < 2; n++) acc[m][n] = (v4f){0.f, 0.f, 0.f, 0.f};

    for (int k0 = 0; k0 < K; k0 += 64) {
        #pragma unroll
        for (int i = 0; i < 4; i++) {
            int id = i * 256 + t;
            int r = id >> 3, j = id & 7;
            int gr = min(row0 + r, M - 1);
            int4 v = *(const int4*)(A + (size_t)gr * K + k0 + j * 8);
            *(int4*)&As[r][j * 8] = v;
        }
        #pragma unroll
        for (int i = 0; i < 2; i++) {
            int id = i * 256 + t;
            int r = id >> 3, j = id & 7;
            int4 v = *(const int4*)(W + (size_t)(col0 + r) * K + k0 + j * 8);
            *(int4*)&Ws[r][j * 8] = v;
        }
        __syncthreads();
        #pragma unroll
        for (int kk = 0; kk < 4; kk++) {
            v4h a[4], bf[2];
            #pragma unroll
            for (int m = 0; m < 4; m++)
                a[m] = *(const v4h*)&As[wrow0 + m * 16 + col16][kk * 16 + grp * 4];
            #pragma unroll
            for (int n = 0; n < 2; n++)
                bf[n] = *(const v4h*)&Ws[wcol0 + n * 16 + col16][kk * 16 + grp * 4];
            #pragma unroll
            for (int m = 0; m < 4; m++)
                #pragma unroll
                for (int n = 0; n < 2; n++)
                    acc[m][n] = mfma16(a[m], bf[n], acc[m][n]);
        }
        __syncthreads();
    }

    #pragma unroll
    for (int n = 0; n < 2; n++) {
        int gcol = col0 + wcol0 + n * 16 + col16;
        float bv = bias[gcol];
        #pragma unroll
        for (int m = 0; m < 4; m++) {
            int rbase = row0 + wrow0 + m * 16 + grp * 4;
            #pragma unroll
            for (int r = 0; r < 4; r++) {
                int grow = rbase + r;
                if (grow >= M) continue;
                float v = acc[m][n][r] + bv;
                int pc = gcol + part_off;
                int part = pc >> 7;
                int h = (pc >> 4) & 7;
                int d = pc & 15;
                int b = Lshift ? (grow >> Lshift) : (grow / L);
                int pos = grow - b * L;
                int bh = b * NH + h;
                if (part == 0)
                    qo[((size_t)bh * L + pos) * 16 + d] = (_Float16)(v * QSCALE);
                else if (part == 1)
                    ko[((size_t)bh * L + pos) * 16 + d] = (_Float16)v;
                else
                    vo[((size_t)bh * 16 + d) * Lkp + pos] = (_Float16)v;
            }
        }
    }
}

// ---------------------------------------------------------------- fused row-local tail
// (R19 proven body; phase A merge extended to NSPL=4 split-KV partials)
// CROSS=1 (decoder): merge(split-KV) -> outproj+LN1 -> crossQ -> cross-attn -> outproj+LN2 -> FFN+LN3
// CROSS=0 (encoder): A(global) -> outproj+LN1 -> FFN+LN2
// BM=32, 128 threads = 2 waves. All intermediates stay in LDS. LDS total 116,736 B.
template<int CROSS>
__global__ __launch_bounds__(128) void post_ln(
    const _Float16* __restrict__ A,
    const _Float16* __restrict__ po, const float* __restrict__ pm, const float* __restrict__ pl,
    const _Float16* __restrict__ Wo1, const float* __restrict__ bo1,
    const _Float16* __restrict__ resg,
    const float* __restrict__ g1, const float* __restrict__ bt1,
    const _Float16* __restrict__ Wq, const float* __restrict__ bq,
    const _Float16* __restrict__ KC_l, const _Float16* __restrict__ VC_l,
    const _Float16* __restrict__ Wo2, const float* __restrict__ bo2,
    const float* __restrict__ g2, const float* __restrict__ bt2,
    const _Float16* __restrict__ W1, const float* __restrict__ fb1,
    const _Float16* __restrict__ W2, const float* __restrict__ fb2,
    const float* __restrict__ g3, const float* __restrict__ bt3,
    _Float16* __restrict__ yout, int M)
{
    __shared__ _Float16 As[32][136];
    __shared__ _Float16 Ws[128][132];
    __shared__ _Float16 YL[32][136];
    __shared__ _Float16 QS[32][136];
    __shared__ _Float16 Khs[2][2048];
    __shared__ _Float16 Vhs[2][2048];
    __shared__ _Float16 W1s[64][136];
    __shared__ _Float16 Hs[32][72];
    __shared__ _Float16 W2s[128][72];
    const int t = threadIdx.x;
    const int wave = t >> 6, lane = t & 63;
    const int col16 = lane & 15, grp = lane >> 4;
    const int row0 = blockIdx.x * 32;
    const int rl = wave * 16 + grp * 4;

    // ================= phase A: (merge | load A) full width + out-proj GEMM (single round) =================
    v4f acc[8];
    #pragma unroll
    for (int n = 0; n < 8; n++) acc[n] = (v4f){0.f, 0.f, 0.f, 0.f};
    #pragma unroll
    for (int i = 0; i < 4; i++) {
        int id = i * 128 + t;
        int r = id >> 4, j = id & 15;
        int grow = min(row0 + r, M - 1);
        if (CROSS) {
            int dim0 = j * 8;
            int h = dim0 >> 4;
            int doff = dim0 & 8;
            int b = grow >> 11, q = grow & 2047;
            size_t idx[NSPL];
            float mm[NSPL], ll[NSPL];
            #pragma unroll
            for (int s2 = 0; s2 < NSPL; s2++) {
                idx[s2] = ((size_t)(b * NSPL + s2) * NH + h) * T_ + q;
                mm[s2] = pm[idx[s2]];
                ll[s2] = pl[idx[s2]];
            }
            float MM = fmaxf(fmaxf(mm[0], mm[1]), fmaxf(mm[2], mm[3]));
            float w[NSPL];
            float tot = 0.f;
            #pragma unroll
            for (int s2 = 0; s2 < NSPL; s2++) {
                w[s2] = fexp2(mm[s2] - MM) * ll[s2];
                tot += w[s2];
            }
            float inv = 1.0f / tot;
            #pragma unroll
            for (int s2 = 0; s2 < NSPL; s2++) w[s2] *= inv;
            v8h oo[NSPL];
            #pragma unroll
            for (int s2 = 0; s2 < NSPL; s2++)
                oo[s2] = *(const v8h*)&po[idx[s2] * 16 + doff];
            v8h mrg;
            #pragma unroll
            for (int e = 0; e < 8; e++)
                mrg[e] = (_Float16)((float)oo[0][e] * w[0] + (float)oo[1][e] * w[1] +
                                    (float)oo[2][e] * w[2] + (float)oo[3][e] * w[3]);
            *(v8h*)&As[r][j * 8] = mrg;
        } else {
            int4 v = *(const int4*)(A + (size_t)grow * DM + j * 8);
            *(int4*)&As[r][j * 8] = v;
        }
    }
    #pragma unroll
    for (int i = 0; i < 16; i++) {
        int id = i * 128 + t;
        int r = id >> 4, j = id & 15;
        int4 v = *(const int4*)(Wo1 + (size_t)r * DM + j * 8);
        *(int4*)&Ws[r][j * 8] = v;
    }
    __syncthreads();
    #pragma unroll
    for (int kk = 0; kk < 8; kk++) {
        v4h a = *(const v4h*)&As[wave * 16 + col16][kk * 16 + grp * 4];
        #pragma unroll
        for (int n = 0; n < 8; n++) {
            v4h bf = *(const v4h*)&Ws[n * 16 + col16][kk * 16 + grp * 4];
            acc[n] = mfma16(a, bf, acc[n]);
        }
    }
    // epilogue LN1 -> YL
    {
        float bv[8], gv[8], btv[8];
        #pragma unroll
        for (int n = 0; n < 8; n++) {
            bv[n] = bo1[col16 + 16 * n];
            gv[n] = g1[col16 + 16 * n];
            btv[n] = bt1[col16 + 16 * n];
        }
        #pragma unroll
        for (int r = 0; r < 4; r++) {
            int grow = min(row0 + rl + r, M - 1);
            float x[8];
            float sum = 0.f;
            #pragma unroll
            for (int n = 0; n < 8; n++) {
                x[n] = acc[n][r] + bv[n] + (float)resg[(size_t)grow * DM + col16 + 16 * n];
                sum += x[n];
            }
            sum += __shfl_xor(sum, 1, 64);
            sum += __shfl_xor(sum, 2, 64);
            sum += __shfl_xor(sum, 4, 64);
            sum += __shfl_xor(sum, 8, 64);
            float mean = sum * (1.0f / 128.0f);
            float vs = 0.f;
            #pragma unroll
            for (int n = 0; n < 8; n++) { x[n] -= mean; vs += x[n] * x[n]; }
            vs += __shfl_xor(vs, 1, 64);
            vs += __shfl_xor(vs, 2, 64);
            vs += __shfl_xor(vs, 4, 64);
            vs += __shfl_xor(vs, 8, 64);
            float rstd = rsqrtf(vs * (1.0f / 128.0f) + 1e-5f);
            #pragma unroll
            for (int n = 0; n < 8; n++)
                YL[rl + r][col16 + 16 * n] = (_Float16)(x[n] * rstd * gv[n] + btv[n]);
        }
    }
    __syncthreads();

    if (CROSS) {
        // ================= phase B: q = (YL @ Wq^T + bq) * QSCALE -> QS (single round) =================
        v4f qacc[8];
        #pragma unroll
        for (int n = 0; n < 8; n++) qacc[n] = (v4f){0.f, 0.f, 0.f, 0.f};
        #pragma unroll
        for (int i = 0; i < 16; i++) {
            int id = i * 128 + t;
            int r = id >> 4, j = id & 15;
            int4 v = *(const int4*)(Wq + (size_t)r * DM + j * 8);
            *(int4*)&Ws[r][j * 8] = v;
        }
        __syncthreads();
        #pragma unroll
        for (int kk = 0; kk < 8; kk++) {
            v4h a = *(const v4h*)&YL[wave * 16 + col16][kk * 16 + grp * 4];
            #pragma unroll
            for (int n = 0; n < 8; n++) {
                v4h bf = *(const v4h*)&Ws[n * 16 + col16][kk * 16 + grp * 4];
                qacc[n] = mfma16(a, bf, qacc[n]);
            }
        }
        __syncthreads();
        #pragma unroll
        for (int n = 0; n < 8; n++) {
            float bb = bq[n * 16 + col16];
            #pragma unroll
            for (int r = 0; r < 4; r++)
                QS[rl + r][n * 16 + col16] = (_Float16)((qacc[n][r] + bb) * QSCALE);
        }

        // ================= phase C: cross attention, 2 heads per barrier round =================
        const int b = row0 >> 11;
        const char* kbB = (const char*)(KC_l + (size_t)(b * NH) * S_ * DH);
        const char* vbB = (const char*)(VC_l + (size_t)(b * NH) * DH * 128);
        for (int h = 0; h < NH; h += 2) {
            __syncthreads();   // prior pair's K/V reads done (first iter: QS writes visible)
            #pragma unroll
            for (int s = 0; s < 2; s++) {
                int hh = h + s;
                #pragma unroll
                for (int rd = 0; rd < 2; rd++) {
                    int dstB = rd * 2048 + wave * 1024 + lane * 16;
                    int krow = dstB >> 5;
                    int half = (dstB >> 4) & 1;
                    gload_lds16(kbB + (long)hh * 3200 + (long)krow * 32 +
                                ((half ^ ((krow >> 2) & 1)) << 4),
                                (char*)&Khs[s][0] + rd * 2048 + wave * 1024);
                }
                #pragma unroll
                for (int rd = 0; rd < 2; rd++) {
                    int dstB = rd * 2048 + wave * 1024 + lane * 16;
                    int vd = dstB >> 8;
                    int inoff = dstB & 255;
                    gload_lds16(vbB + (long)hh * 4096 + (long)vd * 256 +
                                (inoff ^ ((vd & 7) << 4)),
                                (char*)&Vhs[s][0] + rd * 2048 + wave * 1024);
                }
            }
            __syncthreads();

            #pragma unroll
            for (int s = 0; s < 2; s++) {
                int hh = h + s;
                v4h q_frag = *(const v4h*)&QS[wave * 16 + col16][hh * 16 + grp * 4];
                const int kxor = (col16 & 4) << 2;
                v4f s4[7];
                #pragma unroll
                for (int sub = 0; sub < 7; sub++) {
                    int koff = ((sub * 16 + col16) << 5) + ((grp * 8) ^ kxor);
                    v4h k_frag = *(const v4h*)((const char*)&Khs[s][0] + koff);
                    s4[sub] = mfma16(k_frag, q_frag, (v4f){0.f, 0.f, 0.f, 0.f});
                }
                #pragma unroll
                for (int r = 0; r < 4; r++) {         // mask keys 100..111
                    int key = 96 + grp * 4 + r;
                    if (key >= S_) s4[6][r] = -1e30f;
                }
                float mx = -1e30f;
                #pragma unroll
                for (int sub = 0; sub < 7; sub++)
                    #pragma unroll
                    for (int r = 0; r < 4; r++) mx = fmaxf(mx, s4[sub][r]);
                mx = fmaxf(mx, __shfl_xor(mx, 16, 64));
                mx = fmaxf(mx, __shfl_xor(mx, 32, 64));
                float l = 0.f;
                float p[7][4];
                #pragma unroll
                for (int sub = 0; sub < 7; sub++)
                    #pragma unroll
                    for (int r = 0; r < 4; r++) {
                        p[sub][r] = fexp2(s4[sub][r] - mx);
                        l += p[sub][r];
                    }
                l += __shfl_xor(l, 16, 64);
                l += __shfl_xor(l, 32, 64);
                float inv = 1.0f / l;
                v4f o = {0.f, 0.f, 0.f, 0.f};
                #pragma unroll
                for (int sub = 0; sub < 7; sub++) {
                    v4h ph = { (_Float16)(p[sub][0] * inv), (_Float16)(p[sub][1] * inv),
                               (_Float16)(p[sub][2] * inv), (_Float16)(p[sub][3] * inv) };
                    int vbyte = (col16 << 8) + ((sub * 32 + grp * 8) ^ ((col16 & 7) << 4));
                    v4h vt = *(const v4h*)((const char*)&Vhs[s][0] + vbyte);
                    o = mfma16(vt, ph, o);
                }
                #pragma unroll
                for (int r = 0; r < 4; r++)
                    QS[wave * 16 + col16][hh * 16 + grp * 4 + r] = (_Float16)o[r];
            }
        }
        __syncthreads();

        // ================= phase D: out-proj2 + residual(YL) + LN2 -> YL (single round) =================
        v4f ac2[8];
        #pragma unroll
        for (int n = 0; n < 8; n++) ac2[n] = (v4f){0.f, 0.f, 0.f, 0.f};
        #pragma unroll
        for (int i = 0; i < 16; i++) {
            int id = i * 128 + t;
            int r = id >> 4, j = id & 15;
            int4 v = *(const int4*)(Wo2 + (size_t)r * DM + j * 8);
            *(int4*)&Ws[r][j * 8] = v;
        }
        __syncthreads();
        #pragma unroll
        for (int kk = 0; kk < 8; kk++) {
            v4h a = *(const v4h*)&QS[wave * 16 + col16][kk * 16 + grp * 4];
            #pragma unroll
            for (int n = 0; n < 8; n++) {
                v4h bf = *(const v4h*)&Ws[n * 16 + col16][kk * 16 + grp * 4];
                ac2[n] = mfma16(a, bf, ac2[n]);
            }
        }
        {
            float bv[8], gv[8], btv[8];
            #pragma unroll
            for (int n = 0; n < 8; n++) {
                bv[n] = bo2[col16 + 16 * n];
                gv[n] = g2[col16 + 16 * n];
                btv[n] = bt2[col16 + 16 * n];
            }
            #pragma unroll
            for (int r = 0; r < 4; r++) {
                float x[8];
                float sum = 0.f;
                #pragma unroll
                for (int n = 0; n < 8; n++) {
                    x[n] = ac2[n][r] + bv[n] + (float)YL[rl + r][col16 + 16 * n];
                    sum += x[n];
                }
                sum += __shfl_xor(sum, 1, 64);
                sum += __shfl_xor(sum, 2, 64);
                sum += __shfl_xor(sum, 4, 64);
                sum += __shfl_xor(sum, 8, 64);
                float mean = sum * (1.0f / 128.0f);
                float vs = 0.f;
                #pragma unroll
                for (int n = 0; n < 8; n++) { x[n] -= mean; vs += x[n] * x[n]; }
                vs += __shfl_xor(vs, 1, 64);
                vs += __shfl_xor(vs, 2, 64);
                vs += __shfl_xor(vs, 4, 64);
                vs += __shfl_xor(vs, 8, 64);
                float rstd = rsqrtf(vs * (1.0f / 128.0f) + 1e-5f);
                #pragma unroll
                for (int n = 0; n < 8; n++)
                    YL[rl + r][col16 + 16 * n] = (_Float16)(x[n] * rstd * gv[n] + btv[n]);
            }
        }
        __syncthreads();
    }

    // ================= phase E: FFN from YL + residual(YL) + final LN -> yout =================
    v4f oacc[8];
    #pragma unroll
    for (int n = 0; n < 8; n++) oacc[n] = (v4f){0.f, 0.f, 0.f, 0.f};
    for (int hc = 0; hc < 8; hc++) {
        #pragma unroll
        for (int rd = 0; rd < 8; rd++) {
            int id = rd * 128 + t;
            int r = id >> 4, j = id & 15;
            int4 v = *(const int4*)(W1 + (size_t)(hc * 64 + r) * DM + j * 8);
            *(int4*)&W1s[r][j * 8] = v;
        }
        #pragma unroll
        for (int rd = 0; rd < 8; rd++) {
            int id = rd * 128 + t;
            int r = id >> 3, j = id & 7;
            int4 v = *(const int4*)(W2 + (size_t)r * DFFN + hc * 64 + j * 8);
            *(int4*)&W2s[r][j * 8] = v;
        }
        __syncthreads();
        v4f hacc[4];
        #pragma unroll
        for (int n = 0; n < 4; n++) hacc[n] = (v4f){0.f, 0.f, 0.f, 0.f};
        #pragma unroll
        for (int kk = 0; kk < 8; kk++) {
            v4h a = *(const v4h*)&YL[wave * 16 + col16][kk * 16 + grp * 4];
            #pragma unroll
            for (int n = 0; n < 4; n++) {
                v4h bf = *(const v4h*)&W1s[n * 16 + col16][kk * 16 + grp * 4];
                hacc[n] = mfma16(a, bf, hacc[n]);
            }
        }
        #pragma unroll
        for (int n = 0; n < 4; n++) {
            float bb = fb1[hc * 64 + n * 16 + col16];
            #pragma unroll
            for (int r = 0; r < 4; r++) {
                float h = fmaxf(hacc[n][r] + bb, 0.f);
                Hs[rl + r][n * 16 + col16] = (_Float16)h;
            }
        }
        #pragma unroll
        for (int kk = 0; kk < 4; kk++) {
            v4h a = *(const v4h*)&Hs[wave * 16 + col16][kk * 16 + grp * 4];
            #pragma unroll
            for (int n = 0; n < 8; n++) {
                v4h bf = *(const v4h*)&W2s[n * 16 + col16][kk * 16 + grp * 4];
                oacc[n] = mfma16(a, bf, oacc[n]);
            }
        }
        __syncthreads();
    }
    {
        float bv[8], gv[8], btv[8];
        #pragma unroll
        for (int n = 0; n < 8; n++) {
            bv[n] = fb2[col16 + 16 * n];
            gv[n] = g3[col16 + 16 * n];
            btv[n] = bt3[col16 + 16 * n];
        }
        #pragma unroll
        for (int r = 0; r < 4; r++) {
            int row = row0 + rl + r;
            float x[8];
            float sum = 0.f;
            #pragma unroll
            for (int n = 0; n < 8; n++) {
                x[n] = oacc[n][r] + bv[n] + (float)YL[rl + r][col16 + 16 * n];
                sum += x[n];
            }
            sum += __shfl_xor(sum, 1, 64);
            sum += __shfl_xor(sum, 2, 64);
            sum += __shfl_xor(sum, 4, 64);
            sum += __shfl_xor(sum, 8, 64);
            float mean = sum * (1.0f / 128.0f);
            float vs = 0.f;
            #pragma unroll
            for (int n = 0; n < 8; n++) { x[n] -= mean; vs += x[n] * x[n]; }
            vs += __shfl_xor(vs, 1, 64);
            vs += __shfl_xor(vs, 2, 64);
            vs += __shfl_xor(vs, 4, 64);
            vs += __shfl_xor(vs, 8, 64);
            float rstd = rsqrtf(vs * (1.0f / 128.0f) + 1e-5f);
            if (row < M) {
                #pragma unroll
                for (int n = 0; n < 8; n++) {
                    float o = x[n] * rstd * gv[n] + btv[n];
                    yout[(size_t)row * DM + col16 + 16 * n] = (_Float16)o;
                }
            }
        }
    }
}

// ---------------------------------------------------------------- MFMA flash attention: LDS dbuf K/V, both swizzled, defer-max
template<int FINAL>
__global__ __launch_bounds__(256, 6) void attn_p3(
    const _Float16* __restrict__ qh, const _Float16* __restrict__ kh,
    const _Float16* __restrict__ vth, _Float16* __restrict__ outh,
    _Float16* __restrict__ po, float* __restrict__ pm, float* __restrict__ pl,
    int Lq, int Lk, int Lkp, int NS)
{
    __shared__ _Float16 KV[2][2048];
    const int zb = blockIdx.z;
    const int b = zb / NS, split = zb - b * NS;
    const int h = blockIdx.y;
    const int wave = threadIdx.x >> 6, lane = threadIdx.x & 63;
    const int col16 = lane & 15, grp = lane >> 4;
    const int bh = b * NH + h;
    const int qrow = (blockIdx.x * 4 + wave) * 16 + col16;
    const int qcl = min(qrow, Lq - 1);

    v4h q_frag = *(const v4h*)(qh + ((size_t)bh * Lq + qcl) * 16 + grp * 4);
    const char* kbB = (const char*)(kh + (size_t)bh * Lk * 16);
    const char* vbB = (const char*)(vth + (size_t)bh * 16 * Lkp);
    const int LkpB = Lkp * 2;

    const int kvLen = Lk / NS;
    const int kv0 = split * kvLen;
    const int kvEnd = kv0 + kvLen;

    const int krow = wave * 32 + (lane >> 1);
    const long ksrc_off = (long)krow * 32 + (((lane & 1) ^ ((krow >> 2) & 1)) << 4);
    const int vd = (wave & 1) * 8 + (lane >> 3);
    const long vsrc_off = (long)vd * LkpB + (((lane & 7) * 16) ^ ((vd & 7) << 4));
    char* ldsK = (char*)&KV[0][0] + wave * 1024;
    char* ldsV = (char*)&KV[0][0] + 2048 + (wave & 1) * 1024;

    auto stage = [&](int buf, int kc) {
        if (wave < 2)
            gload_lds16(kbB + (long)kc * 32 + ksrc_off, ldsK + buf * 4096);
        else
            gload_lds16(vbB + (long)kc * 2 + vsrc_off, ldsV + buf * 4096);
    };

    const int kxor = (col16 & 4) << 2;

    float m = -1e30f;
    v4f l4 = {0.f, 0.f, 0.f, 0.f};
    v4f oa = {0.f, 0.f, 0.f, 0.f}, ob = {0.f, 0.f, 0.f, 0.f};

    stage(0, kv0);
    __syncthreads();

    int nChunks = (kvLen + 63) >> 6;
    int cur = 0;
    for (int ci = 0; ci < nChunks; ci++, cur ^= 1) {
        int kc = kv0 + ci * 64;
        if (ci + 1 < nChunks) stage(cur ^ 1, kc + 64);

        const char* base = (const char*)&KV[cur][0];
        v4f s4[4];
        #pragma unroll
        for (int sub = 0; sub < 4; sub++) {
            int koff = ((sub * 16 + col16) << 5) + ((grp * 8) ^ kxor);
            v4h k_frag = *(const v4h*)(base + koff);
            s4[sub] = mfma16(k_frag, q_frag, (v4f){0.f, 0.f, 0.f, 0.f});
        }
        if (kc + 64 > kvEnd) {
            #pragma unroll
            for (int sub = 0; sub < 4; sub++)
                #pragma unroll
                for (int r = 0; r < 4; r++) {
                    int key = kc + sub * 16 + grp * 4 + r;
                    if (key >= kvEnd) s4[sub][r] = -1e30f;
                }
        }
        float c0 = fmaxf(fmaxf(s4[0][0], s4[0][1]), fmaxf(s4[0][2], s4[0][3]));
        float c1 = fmaxf(fmaxf(s4[1][0], s4[1][1]), fmaxf(s4[1][2], s4[1][3]));
        float c2 = fmaxf(fmaxf(s4[2][0], s4[2][1]), fmaxf(s4[2][2], s4[2][3]));
        float c3 = fmaxf(fmaxf(s4[3][0], s4[3][1]), fmaxf(s4[3][2], s4[3][3]));
        float cm = fmaxf(fmaxf(c0, c1), fmaxf(c2, c3));
        if (__any(cm > m + 8.0f)) {
            float nm = fmaxf(cm, m);
            nm = fmaxf(nm, __shfl_xor(nm, 16, 64));
            nm = fmaxf(nm, __shfl_xor(nm, 32, 64));
            float corr = fexp2(m - nm);
            l4[0] *= corr; l4[1] *= corr; l4[2] *= corr; l4[3] *= corr;
            oa[0] *= corr; oa[1] *= corr; oa[2] *= corr; oa[3] *= corr;
            ob[0] *= corr; ob[1] *= corr; ob[2] *= corr; ob[3] *= corr;
            m = nm;
        }
        v4h ph[4];
        #pragma unroll
        for (int sub = 0; sub < 4; sub++) {
            float p0 = fexp2(s4[sub][0] - m);
            float p1 = fexp2(s4[sub][1] - m);
            float p2 = fexp2(s4[sub][2] - m);
            float p3 = fexp2(s4[sub][3] - m);
            l4[0] += p0; l4[1] += p1; l4[2] += p2; l4[3] += p3;
            ph[sub] = (v4h){ (_Float16)p0, (_Float16)p1, (_Float16)p2, (_Float16)p3 };
        }
        #pragma unroll
        for (int sub = 0; sub < 4; sub++) {
            int vbyte = 2048 + (col16 << 7) + ((sub * 32 + grp * 8) ^ ((col16 & 7) << 4));
            v4h vt_frag = *(const v4h*)(base + vbyte);
            if (sub & 2)
                ob = mfma16(vt_frag, ph[sub], ob);
            else
                oa = mfma16(vt_frag, ph[sub], oa);
        }
        __syncthreads();
    }

    float l = (l4[0] + l4[1]) + (l4[2] + l4[3]);
    l += __shfl_xor(l, 16, 64);
    l += __shfl_xor(l, 32, 64);
    float inv = 1.0f / l;
    v4f o_acc = {oa[0] + ob[0], oa[1] + ob[1], oa[2] + ob[2], oa[3] + ob[3]};
    if (qrow < Lq) {
        v4h ov = { (_Float16)(o_acc[0] * inv), (_Float16)(o_acc[1] * inv),
                   (_Float16)(o_acc[2] * inv), (_Float16)(o_acc[3] * inv) };
        if (FINAL) {
            *(v4h*)(outh + ((size_t)b * Lq + qrow) * DM + h * DH + grp * 4) = ov;
        } else {
            size_t pidx = ((size_t)zb * NH + h) * Lq + qrow;
            *(v4h*)(po + pidx * 16 + grp * 4) = ov;
            if (grp == 0) { pm[pidx] = m; pl[pidx] = l; }
        }
    }
}

// ---------------------------------------------------------------- LayerNorm (f16 in/out, no residual)
__global__ __launch_bounds__(256) void ln_h(
    _Float16* __restrict__ y, const float* __restrict__ g,
    const float* __restrict__ bta, int M)
{
    int row = blockIdx.x * 4 + (threadIdx.x >> 6);
    int lane = threadIdx.x & 63;
    if (row >= M) return;
    _Float16* yr = y + (size_t)row * DM;
    float x0 = (float)yr[lane], x1 = (float)yr[lane + 64];
    float sum = x0 + x1;
    #pragma unroll
    for (int off = 32; off > 0; off >>= 1) sum += __shfl_xor(sum, off, 64);
    float mean = sum * (1.0f / 128.0f);
    float d0 = x0 - mean, d1 = x1 - mean;
    float vs = d0 * d0 + d1 * d1;
    #pragma unroll
    for (int off = 32; off > 0; off >>= 1) vs += __shfl_xor(vs, off, 64);
    float rstd = rsqrtf(vs * (1.0f / 128.0f) + 1e-5f);
    yr[lane]      = (_Float16)(d0 * rstd * g[lane]      + bta[lane]);
    yr[lane + 64] = (_Float16)(d1 * rstd * g[lane + 64] + bta[lane + 64]);
}

// ---------------------------------------------------------------- final: LN(y)*g+b, dot fc, out = tgt + eta*(.)
__global__ __launch_bounds__(256) void final_ln_kernel(
    const _Float16* __restrict__ y, const float* __restrict__ tgt,
    const float* __restrict__ g, const float* __restrict__ bta,
    const float* __restrict__ fcw, const float* __restrict__ fcb,
    float* __restrict__ out)
{
    int row = blockIdx.x * 4 + (threadIdx.x >> 6);
    int lane = threadIdx.x & 63;
    const _Float16* yr = y + (size_t)row * DM;
    float x0 = (float)yr[lane], x1 = (float)yr[lane + 64];
    float sum = x0 + x1;
    #pragma unroll
    for (int off = 32; off > 0; off >>= 1) sum += __shfl_xor(sum, off, 64);
    float mean = sum * (1.0f / 128.0f);
    float d0 = x0 - mean, d1 = x1 - mean;
    float vs = d0 * d0 + d1 * d1;
    #pragma unroll
    for (int off = 32; off > 0; off >>= 1) vs += __shfl_xor(vs, off, 64);
    float rstd = rsqrtf(vs * (1.0f / 128.0f) + 1e-5f);
    float o0 = d0 * rstd * g[lane]      + bta[lane];
    float o1 = d1 * rstd * g[lane + 64] + bta[lane + 64];
    float a = o0 * fcw[lane] + o1 * fcw[lane + 64];
    #pragma unroll
    for (int off = 32; off > 0; off >>= 1) a += __shfl_xor(a, off, 64);
    if (lane == 0) out[row] = tgt[row] + 1.0e-3f * (a + fcb[0]);
}

// ---------------------------------------------------------------- launcher
extern "C" void kernel_launch(void* const* d_in, const int* in_sizes, int n_in,
                              void* d_out, int out_size, void* d_ws, size_t ws_size,
                              hipStream_t stream)
{
    (void)in_sizes; (void)n_in; (void)out_size; (void)ws_size;
    const int*   src     = (const int*)  d_in[0];
    const float* tgt     = (const float*)d_in[1];
    const float* emb     = (const float*)d_in[2];
    const float* femb_w  = (const float*)d_in[3];
    const float* femb_b  = (const float*)d_in[4];
    const float* enc_inw = (const float*)d_in[5];
    const float* enc_inb = (const float*)d_in[6];
    const float* enc_ow  = (const float*)d_in[7];
    const float* enc_ob  = (const float*)d_in[8];
    const float* enc_l1g = (const float*)d_in[9];
    const float* enc_l1b = (const float*)d_in[10];
    const float* enc_l2g = (const float*)d_in[11];
    const float* enc_l2b = (const float*)d_in[12];
    const float* enc_f1w = (const float*)d_in[13];
    const float* enc_f1b = (const float*)d_in[14];
    const float* enc_f2w = (const float*)d_in[15];
    const float* enc_f2b = (const float*)d_in[16];
    const float* enc_ng  = (const float*)d_in[17];
    const float* enc_nb  = (const float*)d_in[18];
    const float* dec_inw = (const float*)d_in[19];
    const float* dec_inb = (const float*)d_in[20];
    const float* dec_ow  = (const float*)d_in[21];
    const float* dec_ob  = (const float*)d_in[22];
    const float* dec_cinw= (const float*)d_in[23];
    const float* dec_cinb= (const float*)d_in[24];
    const float* dec_cow = (const float*)d_in[25];
    const float* dec_cob = (const float*)d_in[26];
    const float* dec_l1g = (const float*)d_in[27];
    const float* dec_l1b = (const float*)d_in[28];
    const float* dec_l2g = (const float*)d_in[29];
    const float* dec_l2b = (const float*)d_in[30];
    const float* dec_l3g = (const float*)d_in[31];
    const float* dec_l3b = (const float*)d_in[32];
    const float* dec_f1w = (const float*)d_in[33];
    const float* dec_f1b = (const float*)d_in[34];
    const float* dec_f2w = (const float*)d_in[35];
    const float* dec_f2b = (const float*)d_in[36];
    const float* dec_ng  = (const float*)d_in[37];
    const float* dec_nb  = (const float*)d_in[38];
    const float* fc_w    = (const float*)d_in[39];
    const float* fc_b    = (const float*)d_in[40];

    // ---- workspace layout (NSPL=4 split-KV) ----
    float* ws = (float*)d_ws;
    float* pm   = ws;                        // 262144 f32 (4*4*8*2048)
    float* pl   = ws + 262144;               // 262144 f32
    _Float16* hb = (_Float16*)(ws + 524288);
    _Float16* mem_h  = hb;                   // 51200
    _Float16* ybuf_h = hb + 51200;           // 1048576
    _Float16* aout_h = hb + 1099776;         // 1048576
    _Float16* wh     = hb + 2148352;         // 2752512
    _Float16* po     = hb + 4900864;         // 4194304 (normalized f16 partials, NSPL=4)
    _Float16* QH     = hb + 11192320;        // 1048576
    _Float16* KH     = hb + 12240896;        // 1048576
    _Float16* VTH    = hb + 13289472;        // 1048576
    _Float16* KC     = hb + 14338048;        // 307200 (6 layers x 4*8*100*16)
    _Float16* VC     = hb + 14645248;        // 393216 (6 layers x 4*8*16*128)

    const long W_ENC_INW = 0,       W_ENC_OW = 294912,  W_ENC_F1W = 393216,  W_ENC_F2W = 786432;
    const long W_DEC_INW = 1179648, W_DEC_OW = 1474560, W_DEC_CINW = 1572864, W_DEC_COW = 1867776;
    const long W_DEC_F1W = 1966080, W_DEC_F2W = 2359296;

    conv_w<<<dim3(384, 10), 256, 0, stream>>>(enc_inw, enc_ow, enc_f1w, enc_f2w,
                                              dec_inw, dec_ow, dec_cinw, dec_cow,
                                              dec_f1w, dec_f2w, wh);

    // ---------------- encoder (M = 400 rows) ----------------
    embed_src_kernel<<<200, 256, 0, stream>>>(src, emb, mem_h);
    for (int i = 0; i < NL; i++) {
        gemm_h<2><<<dim3(4, 6), 256, 0, stream>>>(mem_h, wh + W_ENC_INW + i * 49152, enc_inb + i * 384,
            nullptr, QH, KH, VTH, 400, 384, 128, 100, 128, 0, 0, 0, 0, 0, 0);
        attn_p3<1><<<dim3(2, NH, B_), 256, 0, stream>>>(QH, KH, VTH, aout_h,
            nullptr, nullptr, nullptr, 100, 100, 128, 1);
        post_ln<0><<<13, 128, 0, stream>>>(aout_h,
            nullptr, nullptr, nullptr,
            wh + W_ENC_OW + i * 16384, enc_ob + i * 128,
            mem_h, enc_l1g + i * 128, enc_l1b + i * 128,
            nullptr, nullptr, nullptr, nullptr, nullptr, nullptr, nullptr, nullptr,
            wh + W_ENC_F1W + i * 65536, enc_f1b + i * 512,
            wh + W_ENC_F2W + i * 65536, enc_f2b + i * 128,
            enc_l2g + i * 128, enc_l2b + i * 128,
            mem_h, 400);
    }
    ln_h<<<100, 256, 0, stream>>>(mem_h, enc_ng, enc_nb, 400);
    // cross K/V packs for ALL 6 decoder layers, one launch
    gemm_h<2><<<dim3(4, 4, 6), 256, 0, stream>>>(mem_h, wh + W_DEC_CINW + 16384, dec_cinb + 128,
        nullptr, nullptr, KC, VC, 400, 256, 128, 100, 128, 128, 0,
        49152, 384, 51200, 65536);

    // ---------------- decoder (M = 8192 rows) ----------------
    embed_tgt_kernel<<<4096, 256, 0, stream>>>(tgt, femb_w, femb_b, ybuf_h);
    for (int i = 0; i < NL; i++) {
        gemm_h<2><<<dim3(64, 6), 256, 0, stream>>>(ybuf_h, wh + W_DEC_INW + i * 49152, dec_inb + i * 384,
            nullptr, QH, KH, VTH, 8192, 384, 128, 2048, 2048, 0, 11, 0, 0, 0, 0);
        attn_p3<0><<<dim3(32, NH, B_ * NSPL), 256, 0, stream>>>(QH, KH, VTH, nullptr,
            po, pm, pl, 2048, 2048, 2048, NSPL);
        post_ln<1><<<256, 128, 0, stream>>>(nullptr,
            po, pm, pl,
            wh + W_DEC_OW + i * 16384, dec_ob + i * 128,
            ybuf_h, dec_l1g + i * 128, dec_l1b + i * 128,
            wh + W_DEC_CINW + i * 49152, dec_cinb + i * 384,
            KC + i * 51200, VC + i * 65536,
            wh + W_DEC_COW + i * 16384, dec_cob + i * 128,
            dec_l2g + i * 128, dec_l2b + i * 128,
            wh + W_DEC_F1W + i * 65536, dec_f1b + i * 512,
            wh + W_DEC_F2W + i * 65536, dec_f2b + i * 128,
            dec_l3g + i * 128, dec_l3b + i * 128,
            ybuf_h, 8192);
    }
    final_ln_kernel<<<2048, 256, 0, stream>>>(ybuf_h, tgt, dec_ng, dec_nb, fc_w, fc_b, (float*)d_out);
}

// Round 23
// 697.097 us; speedup vs baseline: 1.0079x; 1.0079x over previous
//
#include <hip/hip_runtime.h>
#include <hip/hip_bf16.h>
#include <math.h>

#define B_ 4
#define S_ 100
#define T_ 2048
#define DM 128
#define NH 8
#define DH 16
#define NL 6
#define DFFN 512

#define SQRT_D 11.313708498984761f   // sqrt(128)
#define LN10K  9.210340371976184f    // ln(10000)
#define QSCALE 0.36067376022224085f  // 0.25 * log2(e)  (softmax in exp2 domain)

typedef _Float16 v4h __attribute__((ext_vector_type(4)));
typedef _Float16 v8h __attribute__((ext_vector_type(8)));
typedef float    v4f __attribute__((ext_vector_type(4)));

__device__ __forceinline__ float fexp2(float x) { return __builtin_amdgcn_exp2f(x); }

__device__ __forceinline__ v4f mfma16(v4h a, v4h b, v4f c) {
    return __builtin_amdgcn_mfma_f32_16x16x16f16(a, b, c, 0, 0, 0);
}

__device__ __forceinline__ void gload_lds16(const void* g, void* l) {
    __builtin_amdgcn_global_load_lds(
        (const __attribute__((address_space(1))) unsigned int*)g,
        (__attribute__((address_space(3))) unsigned int*)l, 16, 0, 0);
}

// ---------------------------------------------------------------- posenc
__device__ __forceinline__ float pe_val(int pos, int d) {
    int i = d >> 1;
    float dv = __expf((float)i * (-2.0f * LN10K / 128.0f));
    float ang = (float)pos * dv;
    return (d & 1) ? __cosf(ang) : __sinf(ang);
}

// ---------------------------------------------------------------- weight f32->f16 conversion (once per call)
__global__ __launch_bounds__(256) void conv_w(
    const float* __restrict__ p0, const float* __restrict__ p1,
    const float* __restrict__ p2, const float* __restrict__ p3,
    const float* __restrict__ p4, const float* __restrict__ p5,
    const float* __restrict__ p6, const float* __restrict__ p7,
    const float* __restrict__ p8, const float* __restrict__ p9,
    _Float16* __restrict__ out)
{
    int seg = blockIdx.y;
    const float* s; int sz; long off;
    switch (seg) {
        case 0: s = p0; sz = 294912; off = 0;       break;
        case 1: s = p1; sz = 98304;  off = 294912;  break;
        case 2: s = p2; sz = 393216; off = 393216;  break;
        case 3: s = p3; sz = 393216; off = 786432;  break;
        case 4: s = p4; sz = 294912; off = 1179648; break;
        case 5: s = p5; sz = 98304;  off = 1474560; break;
        case 6: s = p6; sz = 294912; off = 1572864; break;
        case 7: s = p7; sz = 98304;  off = 1867776; break;
        case 8: s = p8; sz = 393216; off = 1966080; break;
        default: s = p9; sz = 393216; off = 2359296; break;
    }
    int idx = (blockIdx.x * 256 + threadIdx.x) * 4;
    if (idx >= sz) return;
    float4 v = *(const float4*)(s + idx);
    v4h h = { (_Float16)v.x, (_Float16)v.y, (_Float16)v.z, (_Float16)v.w };
    *(v4h*)(out + off + idx) = h;
}

// ---------------------------------------------------------------- embeds (f16)
__global__ __launch_bounds__(256) void embed_src_kernel(
    const int* __restrict__ src, const float* __restrict__ emb,
    _Float16* __restrict__ outh)
{
    int idx = blockIdx.x * 256 + threadIdx.x;
    if (idx >= B_ * S_ * DM) return;
    int d = idx & 127;
    int row = idx >> 7;
    int b = row / S_;
    int tok = src[row];
    float v = emb[tok * DM + d] * SQRT_D + pe_val(b, d);
    outh[idx] = (_Float16)v;
}

__global__ __launch_bounds__(256) void embed_tgt_kernel(
    const float* __restrict__ tgt, const float* __restrict__ fw,
    const float* __restrict__ fb, _Float16* __restrict__ outh)
{
    int idx = blockIdx.x * 256 + threadIdx.x;
    if (idx >= B_ * T_ * DM) return;
    int d = idx & 127;
    int row = idx >> 7;
    int b = row >> 11;
    float v = (tgt[row] * fw[d] + fb[d]) * SQRT_D + pe_val(b, d);
    outh[idx] = (_Float16)v;
}

// ---------------------------------------------------------------- f16 MFMA GEMM (NT), BM=128 BN=64 BK=64, 256 thr
// MODE 2: attention pack (q scaled, k, v-transposed); z-strided for multi-layer batch.
template<int MODE>
__global__ __launch_bounds__(256) void gemm_h(
    const _Float16* __restrict__ A, const _Float16* __restrict__ W,
    const float* __restrict__ bias,
    _Float16* __restrict__ Ch,
    _Float16* __restrict__ qo, _Float16* __restrict__ ko, _Float16* __restrict__ vo,
    int M, int N, int K, int L, int Lkp, int part_off, int Lshift,
    long zws, int zbs, long zks, long zvs)
{
    if (MODE == 2) {
        int zi = blockIdx.z;
        W += (size_t)zi * zws;
        bias += (size_t)zi * zbs;
        ko += (size_t)zi * zks;
        vo += (size_t)zi * zvs;
    }
    __shared__ _Float16 As[128][72];
    __shared__ _Float16 Ws[64][72];
    const int t = threadIdx.x;
    const int wave = t >> 6, lane = t & 63;
    const int col16 = lane & 15, grp = lane >> 4;
    const int row0 = blockIdx.x * 128, col0 = blockIdx.y * 64;
    const int wrow0 = (wave >> 1) * 64, wcol0 = (wave & 1) * 32;

    v4f acc[4][2];
    #pragma unroll
    for (int m = 0; m < 4; m++)
        #pragma unroll
        for (int n = 0; n < 2; n++) acc[m][n] = (v4f){0.f, 0.f, 0.f, 0.f};

    for (int k0 = 0; k0 < K; k0 += 64) {
        #pragma unroll
        for (int i = 0; i < 4; i++) {
            int id = i * 256 + t;
            int r = id >> 3, j = id & 7;
            int gr = min(row0 + r, M - 1);
            int4 v = *(const int4*)(A + (size_t)gr * K + k0 + j * 8);
            *(int4*)&As[r][j * 8] = v;
        }
        #pragma unroll
        for (int i = 0; i < 2; i++) {
            int id = i * 256 + t;
            int r = id >> 3, j = id & 7;
            int4 v = *(const int4*)(W + (size_t)(col0 + r) * K + k0 + j * 8);
            *(int4*)&Ws[r][j * 8] = v;
        }
        __syncthreads();
        #pragma unroll
        for (int kk = 0; kk < 4; kk++) {
            v4h a[4], bf[2];
            #pragma unroll
            for (int m = 0; m < 4; m++)
                a[m] = *(const v4h*)&As[wrow0 + m * 16 + col16][kk * 16 + grp * 4];
            #pragma unroll
            for (int n = 0; n < 2; n++)
                bf[n] = *(const v4h*)&Ws[wcol0 + n * 16 + col16][kk * 16 + grp * 4];
            #pragma unroll
            for (int m = 0; m < 4; m++)
                #pragma unroll
                for (int n = 0; n < 2; n++)
                    acc[m][n] = mfma16(a[m], bf[n], acc[m][n]);
        }
        __syncthreads();
    }

    #pragma unroll
    for (int n = 0; n < 2; n++) {
        int gcol = col0 + wcol0 + n * 16 + col16;
        float bv = bias[gcol];
        #pragma unroll
        for (int m = 0; m < 4; m++) {
            int rbase = row0 + wrow0 + m * 16 + grp * 4;
            #pragma unroll
            for (int r = 0; r < 4; r++) {
                int grow = rbase + r;
                if (grow >= M) continue;
                float v = acc[m][n][r] + bv;
                int pc = gcol + part_off;
                int part = pc >> 7;
                int h = (pc >> 4) & 7;
                int d = pc & 15;
                int b = Lshift ? (grow >> Lshift) : (grow / L);
                int pos = grow - b * L;
                int bh = b * NH + h;
                if (part == 0)
                    qo[((size_t)bh * L + pos) * 16 + d] = (_Float16)(v * QSCALE);
                else if (part == 1)
                    ko[((size_t)bh * L + pos) * 16 + d] = (_Float16)v;
                else
                    vo[((size_t)bh * 16 + d) * Lkp + pos] = (_Float16)v;
            }
        }
    }
}

// ---------------------------------------------------------------- fused row-local tail
// (R17 proven body; phases A/B/D single-round full-width staging; phase C 2-head batched)
// CROSS=1 (decoder): merge(split-KV) -> outproj+LN1 -> crossQ -> cross-attn -> outproj+LN2 -> FFN+LN3
// CROSS=0 (encoder): A(global) -> outproj+LN1 -> FFN+LN2
// BM=32, 128 threads = 2 waves. All intermediates stay in LDS. LDS total 116,736 B.
template<int CROSS>
__global__ __launch_bounds__(128) void post_ln(
    const _Float16* __restrict__ A,
    const _Float16* __restrict__ po, const float* __restrict__ pm, const float* __restrict__ pl,
    const _Float16* __restrict__ Wo1, const float* __restrict__ bo1,
    const _Float16* __restrict__ resg,
    const float* __restrict__ g1, const float* __restrict__ bt1,
    const _Float16* __restrict__ Wq, const float* __restrict__ bq,
    const _Float16* __restrict__ KC_l, const _Float16* __restrict__ VC_l,
    const _Float16* __restrict__ Wo2, const float* __restrict__ bo2,
    const float* __restrict__ g2, const float* __restrict__ bt2,
    const _Float16* __restrict__ W1, const float* __restrict__ fb1,
    const _Float16* __restrict__ W2, const float* __restrict__ fb2,
    const float* __restrict__ g3, const float* __restrict__ bt3,
    _Float16* __restrict__ yout, int M)
{
    __shared__ _Float16 As[32][136];
    __shared__ _Float16 Ws[128][132];
    __shared__ _Float16 YL[32][136];
    __shared__ _Float16 QS[32][136];
    __shared__ _Float16 Khs[2][2048];
    __shared__ _Float16 Vhs[2][2048];
    __shared__ _Float16 W1s[64][136];
    __shared__ _Float16 Hs[32][72];
    __shared__ _Float16 W2s[128][72];
    const int t = threadIdx.x;
    const int wave = t >> 6, lane = t & 63;
    const int col16 = lane & 15, grp = lane >> 4;
    const int row0 = blockIdx.x * 32;
    const int rl = wave * 16 + grp * 4;

    // ================= phase A: (merge | load A) full width + out-proj GEMM (single round) =================
    v4f acc[8];
    #pragma unroll
    for (int n = 0; n < 8; n++) acc[n] = (v4f){0.f, 0.f, 0.f, 0.f};
    #pragma unroll
    for (int i = 0; i < 4; i++) {
        int id = i * 128 + t;
        int r = id >> 4, j = id & 15;
        int grow = min(row0 + r, M - 1);
        if (CROSS) {
            int dim0 = j * 8;
            int h = dim0 >> 4;
            int doff = dim0 & 8;
            int b = grow >> 11, q = grow & 2047;
            size_t i0 = ((size_t)(b * 2 + 0) * NH + h) * T_ + q;
            size_t i1 = ((size_t)(b * 2 + 1) * NH + h) * T_ + q;
            float m0 = pm[i0], m1 = pm[i1];
            float MM = fmaxf(m0, m1);
            float w0 = fexp2(m0 - MM) * pl[i0];
            float w1 = fexp2(m1 - MM) * pl[i1];
            float inv = 1.0f / (w0 + w1);
            w0 *= inv; w1 *= inv;
            v8h o0 = *(const v8h*)&po[i0 * 16 + doff];
            v8h o1 = *(const v8h*)&po[i1 * 16 + doff];
            v8h mrg;
            #pragma unroll
            for (int e = 0; e < 8; e++)
                mrg[e] = (_Float16)((float)o0[e] * w0 + (float)o1[e] * w1);
            *(v8h*)&As[r][j * 8] = mrg;
        } else {
            int4 v = *(const int4*)(A + (size_t)grow * DM + j * 8);
            *(int4*)&As[r][j * 8] = v;
        }
    }
    #pragma unroll
    for (int i = 0; i < 16; i++) {
        int id = i * 128 + t;
        int r = id >> 4, j = id & 15;
        int4 v = *(const int4*)(Wo1 + (size_t)r * DM + j * 8);
        *(int4*)&Ws[r][j * 8] = v;
    }
    __syncthreads();
    #pragma unroll
    for (int kk = 0; kk < 8; kk++) {
        v4h a = *(const v4h*)&As[wave * 16 + col16][kk * 16 + grp * 4];
        #pragma unroll
        for (int n = 0; n < 8; n++) {
            v4h bf = *(const v4h*)&Ws[n * 16 + col16][kk * 16 + grp * 4];
            acc[n] = mfma16(a, bf, acc[n]);
        }
    }
    // epilogue LN1 -> YL
    {
        float bv[8], gv[8], btv[8];
        #pragma unroll
        for (int n = 0; n < 8; n++) {
            bv[n] = bo1[col16 + 16 * n];
            gv[n] = g1[col16 + 16 * n];
            btv[n] = bt1[col16 + 16 * n];
        }
        #pragma unroll
        for (int r = 0; r < 4; r++) {
            int grow = min(row0 + rl + r, M - 1);
            float x[8];
            float sum = 0.f;
            #pragma unroll
            for (int n = 0; n < 8; n++) {
                x[n] = acc[n][r] + bv[n] + (float)resg[(size_t)grow * DM + col16 + 16 * n];
                sum += x[n];
            }
            sum += __shfl_xor(sum, 1, 64);
            sum += __shfl_xor(sum, 2, 64);
            sum += __shfl_xor(sum, 4, 64);
            sum += __shfl_xor(sum, 8, 64);
            float mean = sum * (1.0f / 128.0f);
            float vs = 0.f;
            #pragma unroll
            for (int n = 0; n < 8; n++) { x[n] -= mean; vs += x[n] * x[n]; }
            vs += __shfl_xor(vs, 1, 64);
            vs += __shfl_xor(vs, 2, 64);
            vs += __shfl_xor(vs, 4, 64);
            vs += __shfl_xor(vs, 8, 64);
            float rstd = rsqrtf(vs * (1.0f / 128.0f) + 1e-5f);
            #pragma unroll
            for (int n = 0; n < 8; n++)
                YL[rl + r][col16 + 16 * n] = (_Float16)(x[n] * rstd * gv[n] + btv[n]);
        }
    }
    __syncthreads();

    if (CROSS) {
        // ================= phase B: q = (YL @ Wq^T + bq) * QSCALE -> QS (single round) =================
        v4f qacc[8];
        #pragma unroll
        for (int n = 0; n < 8; n++) qacc[n] = (v4f){0.f, 0.f, 0.f, 0.f};
        #pragma unroll
        for (int i = 0; i < 16; i++) {
            int id = i * 128 + t;
            int r = id >> 4, j = id & 15;
            int4 v = *(const int4*)(Wq + (size_t)r * DM + j * 8);
            *(int4*)&Ws[r][j * 8] = v;
        }
        __syncthreads();
        #pragma unroll
        for (int kk = 0; kk < 8; kk++) {
            v4h a = *(const v4h*)&YL[wave * 16 + col16][kk * 16 + grp * 4];
            #pragma unroll
            for (int n = 0; n < 8; n++) {
                v4h bf = *(const v4h*)&Ws[n * 16 + col16][kk * 16 + grp * 4];
                qacc[n] = mfma16(a, bf, qacc[n]);
            }
        }
        __syncthreads();
        #pragma unroll
        for (int n = 0; n < 8; n++) {
            float bb = bq[n * 16 + col16];
            #pragma unroll
            for (int r = 0; r < 4; r++)
                QS[rl + r][n * 16 + col16] = (_Float16)((qacc[n][r] + bb) * QSCALE);
        }

        // ================= phase C: cross attention, 2 heads per barrier round =================
        const int b = row0 >> 11;
        const char* kbB = (const char*)(KC_l + (size_t)(b * NH) * S_ * DH);
        const char* vbB = (const char*)(VC_l + (size_t)(b * NH) * DH * 128);
        for (int h = 0; h < NH; h += 2) {
            __syncthreads();   // prior pair's K/V reads done (first iter: QS writes visible)
            #pragma unroll
            for (int s = 0; s < 2; s++) {
                int hh = h + s;
                #pragma unroll
                for (int rd = 0; rd < 2; rd++) {
                    int dstB = rd * 2048 + wave * 1024 + lane * 16;
                    int krow = dstB >> 5;
                    int half = (dstB >> 4) & 1;
                    gload_lds16(kbB + (long)hh * 3200 + (long)krow * 32 +
                                ((half ^ ((krow >> 2) & 1)) << 4),
                                (char*)&Khs[s][0] + rd * 2048 + wave * 1024);
                }
                #pragma unroll
                for (int rd = 0; rd < 2; rd++) {
                    int dstB = rd * 2048 + wave * 1024 + lane * 16;
                    int vd = dstB >> 8;
                    int inoff = dstB & 255;
                    gload_lds16(vbB + (long)hh * 4096 + (long)vd * 256 +
                                (inoff ^ ((vd & 7) << 4)),
                                (char*)&Vhs[s][0] + rd * 2048 + wave * 1024);
                }
            }
            __syncthreads();

            #pragma unroll
            for (int s = 0; s < 2; s++) {
                int hh = h + s;
                v4h q_frag = *(const v4h*)&QS[wave * 16 + col16][hh * 16 + grp * 4];
                const int kxor = (col16 & 4) << 2;
                v4f s4[7];
                #pragma unroll
                for (int sub = 0; sub < 7; sub++) {
                    int koff = ((sub * 16 + col16) << 5) + ((grp * 8) ^ kxor);
                    v4h k_frag = *(const v4h*)((const char*)&Khs[s][0] + koff);
                    s4[sub] = mfma16(k_frag, q_frag, (v4f){0.f, 0.f, 0.f, 0.f});
                }
                #pragma unroll
                for (int r = 0; r < 4; r++) {         // mask keys 100..111
                    int key = 96 + grp * 4 + r;
                    if (key >= S_) s4[6][r] = -1e30f;
                }
                float mx = -1e30f;
                #pragma unroll
                for (int sub = 0; sub < 7; sub++)
                    #pragma unroll
                    for (int r = 0; r < 4; r++) mx = fmaxf(mx, s4[sub][r]);
                mx = fmaxf(mx, __shfl_xor(mx, 16, 64));
                mx = fmaxf(mx, __shfl_xor(mx, 32, 64));
                float l = 0.f;
                float p[7][4];
                #pragma unroll
                for (int sub = 0; sub < 7; sub++)
                    #pragma unroll
                    for (int r = 0; r < 4; r++) {
                        p[sub][r] = fexp2(s4[sub][r] - mx);
                        l += p[sub][r];
                    }
                l += __shfl_xor(l, 16, 64);
                l += __shfl_xor(l, 32, 64);
                float inv = 1.0f / l;
                v4f o = {0.f, 0.f, 0.f, 0.f};
                #pragma unroll
                for (int sub = 0; sub < 7; sub++) {
                    v4h ph = { (_Float16)(p[sub][0] * inv), (_Float16)(p[sub][1] * inv),
                               (_Float16)(p[sub][2] * inv), (_Float16)(p[sub][3] * inv) };
                    int vbyte = (col16 << 8) + ((sub * 32 + grp * 8) ^ ((col16 & 7) << 4));
                    v4h vt = *(const v4h*)((const char*)&Vhs[s][0] + vbyte);
                    o = mfma16(vt, ph, o);
                }
                #pragma unroll
                for (int r = 0; r < 4; r++)
                    QS[wave * 16 + col16][hh * 16 + grp * 4 + r] = (_Float16)o[r];
            }
        }
        __syncthreads();

        // ================= phase D: out-proj2 + residual(YL) + LN2 -> YL (single round) =================
        v4f ac2[8];
        #pragma unroll
        for (int n = 0; n < 8; n++) ac2[n] = (v4f){0.f, 0.f, 0.f, 0.f};
        #pragma unroll
        for (int i = 0; i < 16; i++) {
            int id = i * 128 + t;
            int r = id >> 4, j = id & 15;
            int4 v = *(const int4*)(Wo2 + (size_t)r * DM + j * 8);
            *(int4*)&Ws[r][j * 8] = v;
        }
        __syncthreads();
        #pragma unroll
        for (int kk = 0; kk < 8; kk++) {
            v4h a = *(const v4h*)&QS[wave * 16 + col16][kk * 16 + grp * 4];
            #pragma unroll
            for (int n = 0; n < 8; n++) {
                v4h bf = *(const v4h*)&Ws[n * 16 + col16][kk * 16 + grp * 4];
                ac2[n] = mfma16(a, bf, ac2[n]);
            }
        }
        {
            float bv[8], gv[8], btv[8];
            #pragma unroll
            for (int n = 0; n < 8; n++) {
                bv[n] = bo2[col16 + 16 * n];
                gv[n] = g2[col16 + 16 * n];
                btv[n] = bt2[col16 + 16 * n];
            }
            #pragma unroll
            for (int r = 0; r < 4; r++) {
                float x[8];
                float sum = 0.f;
                #pragma unroll
                for (int n = 0; n < 8; n++) {
                    x[n] = ac2[n][r] + bv[n] + (float)YL[rl + r][col16 + 16 * n];
                    sum += x[n];
                }
                sum += __shfl_xor(sum, 1, 64);
                sum += __shfl_xor(sum, 2, 64);
                sum += __shfl_xor(sum, 4, 64);
                sum += __shfl_xor(sum, 8, 64);
                float mean = sum * (1.0f / 128.0f);
                float vs = 0.f;
                #pragma unroll
                for (int n = 0; n < 8; n++) { x[n] -= mean; vs += x[n] * x[n]; }
                vs += __shfl_xor(vs, 1, 64);
                vs += __shfl_xor(vs, 2, 64);
                vs += __shfl_xor(vs, 4, 64);
                vs += __shfl_xor(vs, 8, 64);
                float rstd = rsqrtf(vs * (1.0f / 128.0f) + 1e-5f);
                #pragma unroll
                for (int n = 0; n < 8; n++)
                    YL[rl + r][col16 + 16 * n] = (_Float16)(x[n] * rstd * gv[n] + btv[n]);
            }
        }
        __syncthreads();
    }

    // ================= phase E: FFN from YL + residual(YL) + final LN -> yout =================
    v4f oacc[8];
    #pragma unroll
    for (int n = 0; n < 8; n++) oacc[n] = (v4f){0.f, 0.f, 0.f, 0.f};
    for (int hc = 0; hc < 8; hc++) {
        #pragma unroll
        for (int rd = 0; rd < 8; rd++) {
            int id = rd * 128 + t;
            int r = id >> 4, j = id & 15;
            int4 v = *(const int4*)(W1 + (size_t)(hc * 64 + r) * DM + j * 8);
            *(int4*)&W1s[r][j * 8] = v;
        }
        #pragma unroll
        for (int rd = 0; rd < 8; rd++) {
            int id = rd * 128 + t;
            int r = id >> 3, j = id & 7;
            int4 v = *(const int4*)(W2 + (size_t)r * DFFN + hc * 64 + j * 8);
            *(int4*)&W2s[r][j * 8] = v;
        }
        __syncthreads();
        v4f hacc[4];
        #pragma unroll
        for (int n = 0; n < 4; n++) hacc[n] = (v4f){0.f, 0.f, 0.f, 0.f};
        #pragma unroll
        for (int kk = 0; kk < 8; kk++) {
            v4h a = *(const v4h*)&YL[wave * 16 + col16][kk * 16 + grp * 4];
            #pragma unroll
            for (int n = 0; n < 4; n++) {
                v4h bf = *(const v4h*)&W1s[n * 16 + col16][kk * 16 + grp * 4];
                hacc[n] = mfma16(a, bf, hacc[n]);
            }
        }
        #pragma unroll
        for (int n = 0; n < 4; n++) {
            float bb = fb1[hc * 64 + n * 16 + col16];
            #pragma unroll
            for (int r = 0; r < 4; r++) {
                float h = fmaxf(hacc[n][r] + bb, 0.f);
                Hs[rl + r][n * 16 + col16] = (_Float16)h;
            }
        }
        #pragma unroll
        for (int kk = 0; kk < 4; kk++) {
            v4h a = *(const v4h*)&Hs[wave * 16 + col16][kk * 16 + grp * 4];
            #pragma unroll
            for (int n = 0; n < 8; n++) {
                v4h bf = *(const v4h*)&W2s[n * 16 + col16][kk * 16 + grp * 4];
                oacc[n] = mfma16(a, bf, oacc[n]);
            }
        }
        __syncthreads();
    }
    {
        float bv[8], gv[8], btv[8];
        #pragma unroll
        for (int n = 0; n < 8; n++) {
            bv[n] = fb2[col16 + 16 * n];
            gv[n] = g3[col16 + 16 * n];
            btv[n] = bt3[col16 + 16 * n];
        }
        #pragma unroll
        for (int r = 0; r < 4; r++) {
            int row = row0 + rl + r;
            float x[8];
            float sum = 0.f;
            #pragma unroll
            for (int n = 0; n < 8; n++) {
                x[n] = oacc[n][r] + bv[n] + (float)YL[rl + r][col16 + 16 * n];
                sum += x[n];
            }
            sum += __shfl_xor(sum, 1, 64);
            sum += __shfl_xor(sum, 2, 64);
            sum += __shfl_xor(sum, 4, 64);
            sum += __shfl_xor(sum, 8, 64);
            float mean = sum * (1.0f / 128.0f);
            float vs = 0.f;
            #pragma unroll
            for (int n = 0; n < 8; n++) { x[n] -= mean; vs += x[n] * x[n]; }
            vs += __shfl_xor(vs, 1, 64);
            vs += __shfl_xor(vs, 2, 64);
            vs += __shfl_xor(vs, 4, 64);
            vs += __shfl_xor(vs, 8, 64);
            float rstd = rsqrtf(vs * (1.0f / 128.0f) + 1e-5f);
            if (row < M) {
                #pragma unroll
                for (int n = 0; n < 8; n++) {
                    float o = x[n] * rstd * gv[n] + btv[n];
                    yout[(size_t)row * DM + col16 + 16 * n] = (_Float16)o;
                }
            }
        }
    }
}

// ---------------------------------------------------------------- MFMA flash attention: LDS dbuf K/V, both swizzled, defer-max
template<int FINAL>
__global__ __launch_bounds__(256, 6) void attn_p3(
    const _Float16* __restrict__ qh, const _Float16* __restrict__ kh,
    const _Float16* __restrict__ vth, _Float16* __restrict__ outh,
    _Float16* __restrict__ po, float* __restrict__ pm, float* __restrict__ pl,
    int Lq, int Lk, int Lkp, int NS)
{
    __shared__ _Float16 KV[2][2048];
    const int zb = blockIdx.z;
    const int b = zb / NS, split = zb - b * NS;
    const int h = blockIdx.y;
    const int wave = threadIdx.x >> 6, lane = threadIdx.x & 63;
    const int col16 = lane & 15, grp = lane >> 4;
    const int bh = b * NH + h;
    const int qrow = (blockIdx.x * 4 + wave) * 16 + col16;
    const int qcl = min(qrow, Lq - 1);

    v4h q_frag = *(const v4h*)(qh + ((size_t)bh * Lq + qcl) * 16 + grp * 4);
    const char* kbB = (const char*)(kh + (size_t)bh * Lk * 16);
    const char* vbB = (const char*)(vth + (size_t)bh * 16 * Lkp);
    const int LkpB = Lkp * 2;

    const int kvLen = Lk / NS;
    const int kv0 = split * kvLen;
    const int kvEnd = kv0 + kvLen;

    const int krow = wave * 32 + (lane >> 1);
    const long ksrc_off = (long)krow * 32 + (((lane & 1) ^ ((krow >> 2) & 1)) << 4);
    const int vd = (wave & 1) * 8 + (lane >> 3);
    const long vsrc_off = (long)vd * LkpB + (((lane & 7) * 16) ^ ((vd & 7) << 4));
    char* ldsK = (char*)&KV[0][0] + wave * 1024;
    char* ldsV = (char*)&KV[0][0] + 2048 + (wave & 1) * 1024;

    auto stage = [&](int buf, int kc) {
        if (wave < 2)
            gload_lds16(kbB + (long)kc * 32 + ksrc_off, ldsK + buf * 4096);
        else
            gload_lds16(vbB + (long)kc * 2 + vsrc_off, ldsV + buf * 4096);
    };

    const int kxor = (col16 & 4) << 2;

    float m = -1e30f;
    v4f l4 = {0.f, 0.f, 0.f, 0.f};
    v4f oa = {0.f, 0.f, 0.f, 0.f}, ob = {0.f, 0.f, 0.f, 0.f};

    stage(0, kv0);
    __syncthreads();

    int nChunks = (kvLen + 63) >> 6;
    int cur = 0;
    for (int ci = 0; ci < nChunks; ci++, cur ^= 1) {
        int kc = kv0 + ci * 64;
        if (ci + 1 < nChunks) stage(cur ^ 1, kc + 64);

        const char* base = (const char*)&KV[cur][0];
        v4f s4[4];
        #pragma unroll
        for (int sub = 0; sub < 4; sub++) {
            int koff = ((sub * 16 + col16) << 5) + ((grp * 8) ^ kxor);
            v4h k_frag = *(const v4h*)(base + koff);
            s4[sub] = mfma16(k_frag, q_frag, (v4f){0.f, 0.f, 0.f, 0.f});
        }
        if (kc + 64 > kvEnd) {
            #pragma unroll
            for (int sub = 0; sub < 4; sub++)
                #pragma unroll
                for (int r = 0; r < 4; r++) {
                    int key = kc + sub * 16 + grp * 4 + r;
                    if (key >= kvEnd) s4[sub][r] = -1e30f;
                }
        }
        float c0 = fmaxf(fmaxf(s4[0][0], s4[0][1]), fmaxf(s4[0][2], s4[0][3]));
        float c1 = fmaxf(fmaxf(s4[1][0], s4[1][1]), fmaxf(s4[1][2], s4[1][3]));
        float c2 = fmaxf(fmaxf(s4[2][0], s4[2][1]), fmaxf(s4[2][2], s4[2][3]));
        float c3 = fmaxf(fmaxf(s4[3][0], s4[3][1]), fmaxf(s4[3][2], s4[3][3]));
        float cm = fmaxf(fmaxf(c0, c1), fmaxf(c2, c3));
        if (__any(cm > m + 8.0f)) {
            float nm = fmaxf(cm, m);
            nm = fmaxf(nm, __shfl_xor(nm, 16, 64));
            nm = fmaxf(nm, __shfl_xor(nm, 32, 64));
            float corr = fexp2(m - nm);
            l4[0] *= corr; l4[1] *= corr; l4[2] *= corr; l4[3] *= corr;
            oa[0] *= corr; oa[1] *= corr; oa[2] *= corr; oa[3] *= corr;
            ob[0] *= corr; ob[1] *= corr; ob[2] *= corr; ob[3] *= corr;
            m = nm;
        }
        v4h ph[4];
        #pragma unroll
        for (int sub = 0; sub < 4; sub++) {
            float p0 = fexp2(s4[sub][0] - m);
            float p1 = fexp2(s4[sub][1] - m);
            float p2 = fexp2(s4[sub][2] - m);
            float p3 = fexp2(s4[sub][3] - m);
            l4[0] += p0; l4[1] += p1; l4[2] += p2; l4[3] += p3;
            ph[sub] = (v4h){ (_Float16)p0, (_Float16)p1, (_Float16)p2, (_Float16)p3 };
        }
        #pragma unroll
        for (int sub = 0; sub < 4; sub++) {
            int vbyte = 2048 + (col16 << 7) + ((sub * 32 + grp * 8) ^ ((col16 & 7) << 4));
            v4h vt_frag = *(const v4h*)(base + vbyte);
            if (sub & 2)
                ob = mfma16(vt_frag, ph[sub], ob);
            else
                oa = mfma16(vt_frag, ph[sub], oa);
        }
        __syncthreads();
    }

    float l = (l4[0] + l4[1]) + (l4[2] + l4[3]);
    l += __shfl_xor(l, 16, 64);
    l += __shfl_xor(l, 32, 64);
    float inv = 1.0f / l;
    v4f o_acc = {oa[0] + ob[0], oa[1] + ob[1], oa[2] + ob[2], oa[3] + ob[3]};
    if (qrow < Lq) {
        v4h ov = { (_Float16)(o_acc[0] * inv), (_Float16)(o_acc[1] * inv),
                   (_Float16)(o_acc[2] * inv), (_Float16)(o_acc[3] * inv) };
        if (FINAL) {
            *(v4h*)(outh + ((size_t)b * Lq + qrow) * DM + h * DH + grp * 4) = ov;
        } else {
            size_t pidx = ((size_t)zb * NH + h) * Lq + qrow;
            *(v4h*)(po + pidx * 16 + grp * 4) = ov;
            if (grp == 0) { pm[pidx] = m; pl[pidx] = l; }
        }
    }
}

// ---------------------------------------------------------------- LayerNorm (f16 in/out, no residual)
__global__ __launch_bounds__(256) void ln_h(
    _Float16* __restrict__ y, const float* __restrict__ g,
    const float* __restrict__ bta, int M)
{
    int row = blockIdx.x * 4 + (threadIdx.x >> 6);
    int lane = threadIdx.x & 63;
    if (row >= M) return;
    _Float16* yr = y + (size_t)row * DM;
    float x0 = (float)yr[lane], x1 = (float)yr[lane + 64];
    float sum = x0 + x1;
    #pragma unroll
    for (int off = 32; off > 0; off >>= 1) sum += __shfl_xor(sum, off, 64);
    float mean = sum * (1.0f / 128.0f);
    float d0 = x0 - mean, d1 = x1 - mean;
    float vs = d0 * d0 + d1 * d1;
    #pragma unroll
    for (int off = 32; off > 0; off >>= 1) vs += __shfl_xor(vs, off, 64);
    float rstd = rsqrtf(vs * (1.0f / 128.0f) + 1e-5f);
    yr[lane]      = (_Float16)(d0 * rstd * g[lane]      + bta[lane]);
    yr[lane + 64] = (_Float16)(d1 * rstd * g[lane + 64] + bta[lane + 64]);
}

// ---------------------------------------------------------------- final: LN(y)*g+b, dot fc, out = tgt + eta*(.)
__global__ __launch_bounds__(256) void final_ln_kernel(
    const _Float16* __restrict__ y, const float* __restrict__ tgt,
    const float* __restrict__ g, const float* __restrict__ bta,
    const float* __restrict__ fcw, const float* __restrict__ fcb,
    float* __restrict__ out)
{
    int row = blockIdx.x * 4 + (threadIdx.x >> 6);
    int lane = threadIdx.x & 63;
    const _Float16* yr = y + (size_t)row * DM;
    float x0 = (float)yr[lane], x1 = (float)yr[lane + 64];
    float sum = x0 + x1;
    #pragma unroll
    for (int off = 32; off > 0; off >>= 1) sum += __shfl_xor(sum, off, 64);
    float mean = sum * (1.0f / 128.0f);
    float d0 = x0 - mean, d1 = x1 - mean;
    float vs = d0 * d0 + d1 * d1;
    #pragma unroll
    for (int off = 32; off > 0; off >>= 1) vs += __shfl_xor(vs, off, 64);
    float rstd = rsqrtf(vs * (1.0f / 128.0f) + 1e-5f);
    float o0 = d0 * rstd * g[lane]      + bta[lane];
    float o1 = d1 * rstd * g[lane + 64] + bta[lane + 64];
    float a = o0 * fcw[lane] + o1 * fcw[lane + 64];
    #pragma unroll
    for (int off = 32; off > 0; off >>= 1) a += __shfl_xor(a, off, 64);
    if (lane == 0) out[row] = tgt[row] + 1.0e-3f * (a + fcb[0]);
}

// ---------------------------------------------------------------- launcher
extern "C" void kernel_launch(void* const* d_in, const int* in_sizes, int n_in,
                              void* d_out, int out_size, void* d_ws, size_t ws_size,
                              hipStream_t stream)
{
    (void)in_sizes; (void)n_in; (void)out_size; (void)ws_size;
    const int*   src     = (const int*)  d_in[0];
    const float* tgt     = (const float*)d_in[1];
    const float* emb     = (const float*)d_in[2];
    const float* femb_w  = (const float*)d_in[3];
    const float* femb_b  = (const float*)d_in[4];
    const float* enc_inw = (const float*)d_in[5];
    const float* enc_inb = (const float*)d_in[6];
    const float* enc_ow  = (const float*)d_in[7];
    const float* enc_ob  = (const float*)d_in[8];
    const float* enc_l1g = (const float*)d_in[9];
    const float* enc_l1b = (const float*)d_in[10];
    const float* enc_l2g = (const float*)d_in[11];
    const float* enc_l2b = (const float*)d_in[12];
    const float* enc_f1w = (const float*)d_in[13];
    const float* enc_f1b = (const float*)d_in[14];
    const float* enc_f2w = (const float*)d_in[15];
    const float* enc_f2b = (const float*)d_in[16];
    const float* enc_ng  = (const float*)d_in[17];
    const float* enc_nb  = (const float*)d_in[18];
    const float* dec_inw = (const float*)d_in[19];
    const float* dec_inb = (const float*)d_in[20];
    const float* dec_ow  = (const float*)d_in[21];
    const float* dec_ob  = (const float*)d_in[22];
    const float* dec_cinw= (const float*)d_in[23];
    const float* dec_cinb= (const float*)d_in[24];
    const float* dec_cow = (const float*)d_in[25];
    const float* dec_cob = (const float*)d_in[26];
    const float* dec_l1g = (const float*)d_in[27];
    const float* dec_l1b = (const float*)d_in[28];
    const float* dec_l2g = (const float*)d_in[29];
    const float* dec_l2b = (const float*)d_in[30];
    const float* dec_l3g = (const float*)d_in[31];
    const float* dec_l3b = (const float*)d_in[32];
    const float* dec_f1w = (const float*)d_in[33];
    const float* dec_f1b = (const float*)d_in[34];
    const float* dec_f2w = (const float*)d_in[35];
    const float* dec_f2b = (const float*)d_in[36];
    const float* dec_ng  = (const float*)d_in[37];
    const float* dec_nb  = (const float*)d_in[38];
    const float* fc_w    = (const float*)d_in[39];
    const float* fc_b    = (const float*)d_in[40];

    // ---- workspace layout ----
    float* ws = (float*)d_ws;
    float* pm   = ws;                        // 131072 f32 (2*4*8*2048)
    float* pl   = ws + 131072;               // 131072 f32
    _Float16* hb = (_Float16*)(ws + 262144);
    _Float16* mem_h  = hb;                   // 51200
    _Float16* ybuf_h = hb + 51200;           // 1048576
    _Float16* aout_h = hb + 1099776;         // 1048576
    _Float16* wh     = hb + 2148352;         // 2752512
    _Float16* po     = hb + 4900864;         // 2097152 (normalized f16 partials)
    _Float16* QH     = hb + 11192320;        // 1048576
    _Float16* KH     = hb + 12240896;        // 1048576
    _Float16* VTH    = hb + 13289472;        // 1048576
    _Float16* KC     = hb + 14338048;        // 307200 (6 layers x 4*8*100*16)
    _Float16* VC     = hb + 14645248;        // 393216 (6 layers x 4*8*16*128)

    const long W_ENC_INW = 0,       W_ENC_OW = 294912,  W_ENC_F1W = 393216,  W_ENC_F2W = 786432;
    const long W_DEC_INW = 1179648, W_DEC_OW = 1474560, W_DEC_CINW = 1572864, W_DEC_COW = 1867776;
    const long W_DEC_F1W = 1966080, W_DEC_F2W = 2359296;

    conv_w<<<dim3(384, 10), 256, 0, stream>>>(enc_inw, enc_ow, enc_f1w, enc_f2w,
                                              dec_inw, dec_ow, dec_cinw, dec_cow,
                                              dec_f1w, dec_f2w, wh);

    // ---------------- encoder (M = 400 rows) ----------------
    embed_src_kernel<<<200, 256, 0, stream>>>(src, emb, mem_h);
    for (int i = 0; i < NL; i++) {
        gemm_h<2><<<dim3(4, 6), 256, 0, stream>>>(mem_h, wh + W_ENC_INW + i * 49152, enc_inb + i * 384,
            nullptr, QH, KH, VTH, 400, 384, 128, 100, 128, 0, 0, 0, 0, 0, 0);
        attn_p3<1><<<dim3(2, NH, B_), 256, 0, stream>>>(QH, KH, VTH, aout_h,
            nullptr, nullptr, nullptr, 100, 100, 128, 1);
        post_ln<0><<<13, 128, 0, stream>>>(aout_h,
            nullptr, nullptr, nullptr,
            wh + W_ENC_OW + i * 16384, enc_ob + i * 128,
            mem_h, enc_l1g + i * 128, enc_l1b + i * 128,
            nullptr, nullptr, nullptr, nullptr, nullptr, nullptr, nullptr, nullptr,
            wh + W_ENC_F1W + i * 65536, enc_f1b + i * 512,
            wh + W_ENC_F2W + i * 65536, enc_f2b + i * 128,
            enc_l2g + i * 128, enc_l2b + i * 128,
            mem_h, 400);
    }
    ln_h<<<100, 256, 0, stream>>>(mem_h, enc_ng, enc_nb, 400);
    // cross K/V packs for ALL 6 decoder layers, one launch
    gemm_h<2><<<dim3(4, 4, 6), 256, 0, stream>>>(mem_h, wh + W_DEC_CINW + 16384, dec_cinb + 128,
        nullptr, nullptr, KC, VC, 400, 256, 128, 100, 128, 128, 0,
        49152, 384, 51200, 65536);

    // ---------------- decoder (M = 8192 rows) ----------------
    embed_tgt_kernel<<<4096, 256, 0, stream>>>(tgt, femb_w, femb_b, ybuf_h);
    for (int i = 0; i < NL; i++) {
        gemm_h<2><<<dim3(64, 6), 256, 0, stream>>>(ybuf_h, wh + W_DEC_INW + i * 49152, dec_inb + i * 384,
            nullptr, QH, KH, VTH, 8192, 384, 128, 2048, 2048, 0, 11, 0, 0, 0, 0);
        attn_p3<0><<<dim3(32, NH, B_ * 2), 256, 0, stream>>>(QH, KH, VTH, nullptr,
            po, pm, pl, 2048, 2048, 2048, 2);
        post_ln<1><<<256, 128, 0, stream>>>(nullptr,
            po, pm, pl,
            wh + W_DEC_OW + i * 16384, dec_ob + i * 128,
            ybuf_h, dec_l1g + i * 128, dec_l1b + i * 128,
            wh + W_DEC_CINW + i * 49152, dec_cinb + i * 384,
            KC + i * 51200, VC + i * 65536,
            wh + W_DEC_COW + i * 16384, dec_cob + i * 128,
            dec_l2g + i * 128, dec_l2b + i * 128,
            wh + W_DEC_F1W + i * 65536, dec_f1b + i * 512,
            wh + W_DEC_F2W + i * 65536, dec_f2b + i * 128,
            dec_l3g + i * 128, dec_l3b + i * 128,
            ybuf_h, 8192);
    }
    final_ln_kernel<<<2048, 256, 0, stream>>>(ybuf_h, tgt, dec_ng, dec_nb, fc_w, fc_b, (float*)d_out);
}